// Round 13
// baseline (395.095 us; speedup 1.0000x reference)
//
#include <hip/hip_runtime.h>
#include <cstdint>
#include <cstddef>

#define DI __device__ __forceinline__

namespace pk {

constexpr int NB1 = 65536;      // stage-1 nodes (B*N)
constexpr int NE  = 1048576;    // edges (B*N*DEG)
constexpr int BG  = 8;          // graphs
constexpr int NPG1 = 8192;      // nodes per graph, stage 1
constexpr int EPG1 = NE/BG;     // edges per graph, stage 1 (131072)
constexpr int KP1 = 2458;       // top-k 1
constexpr int KP2 = 738;        // top-k 2
constexpr int NN2 = BG*KP1;     // 19664
constexpr int NN3 = BG*KP2;     // 5904
constexpr int REG2 = 16384;     // per-graph edge region after pool1 (exp 11.8K±0.1K)
constexpr int REG3 = 4096;      // per-graph edge region after pool2 (exp ~1.1K)
constexpr int CAP2 = BG*REG2;
constexpr int CAP3 = BG*REG3;
constexpr int CPB1 = 16;        // count blocks per graph
constexpr int NTILE = 32;      // 256-node tiles per graph (8192/256)
constexpr int BKT = 5120;       // bucket capacity per (graph,tile): mean 4096 + 16 sigma

// R11 PITFALL (recorded): hipLaunchCooperativeKernel under this harness's
// graph capture produced WRONG RESULTS (absmax 2.8) with phase logic that was
// line-identical to the passing split kernels. Cooperative grid.sync is NOT
// usable here — dependency edges must remain separate dispatches.

DI float lrelu(float x){ return x > 0.f ? x : 0.2f*x; }
DI float eluf(float x){ return x > 0.f ? x : expf(x) - 1.f; }

// XCD-affinity swizzle (heuristic only).
DI int swz_block(){
  int nb = gridDim.x, b = blockIdx.x;
  if((nb & 7) == 0) return (b & 7)*(nb >> 3) + (b >> 3);
  return b;
}

// ---- MERGED stage-1 front: blocks [0,64) = pos@W1 projection (+logits),
// blocks [64,192) = TILE-BUCKET partition (counting sort phase A).
// R4/R5 lessons: no cross-XCD fine-grained atomics, no random 4B scatters.
// The 8192-bin LDS histogram computes per-tile run sizes for the single
// same-XCD reservation atomic per (block,tile); edges packed (sloc<<13)|dloc.
__global__ __launch_bounds__(1024) void k_s1_front(
    const float* __restrict__ pos, const float* __restrict__ W,
    const float* __restrict__ as_, const float* __restrict__ ad_,
    float* __restrict__ xp, float* __restrict__ als, float* __restrict__ ald,
    const int* __restrict__ se, const int* __restrict__ de,
    int* __restrict__ bcur, int* __restrict__ bpk){
  __shared__ int h[NPG1];
  __shared__ int hbase[NTILE];
  __shared__ int hc[NTILE];
  int tid = threadIdx.x;
  if(blockIdx.x < 64){
    // ---- projection part (NB1 = 64*1024 exactly)
    int i = blockIdx.x*1024 + tid;
    float p0=pos[3*i], p1=pos[3*i+1], p2=pos[3*i+2];
    float row[32];
#pragma unroll
    for(int c=0;c<32;c++) row[c] = p0*W[c] + p1*W[32+c] + p2*W[64+c];
    float s0=0.f,d0=0.f,s1=0.f,d1=0.f;
#pragma unroll
    for(int f=0;f<16;f++){
      s0 += row[f]*as_[f];        d0 += row[f]*ad_[f];
      s1 += row[16+f]*as_[16+f];  d1 += row[16+f]*ad_[16+f];
    }
    float4* o = reinterpret_cast<float4*>(xp + (size_t)i*32);
#pragma unroll
    for(int q=0;q<8;q++) o[q] = make_float4(row[4*q],row[4*q+1],row[4*q+2],row[4*q+3]);
    ((float2*)als)[i] = make_float2(s0,s1);
    ((float2*)ald)[i] = make_float2(d0,d1);
    return;
  }
  // ---- bucket partition: 128 blocks = 8 graphs (b&7 -> XCD-affine) x 16 chunks
  int bb = blockIdx.x - 64;
  int g = bb & 7, t = bb >> 3;
  for(int i=tid;i<NPG1;i+=1024) h[i]=0;
  __syncthreads();
  const int4* de4 = (const int4*)(de + g*EPG1 + t*(EPG1/CPB1));
  const int4* se4 = (const int4*)(se + g*EPG1 + t*(EPG1/CPB1));
  int lo = g*NPG1;
  int4 dv[2], sv[2];
#pragma unroll
  for(int j=0;j<2;j++){ dv[j]=de4[j*1024+tid]; sv[j]=se4[j*1024+tid]; }
  int dl[8], sl[8];
#pragma unroll
  for(int j=0;j<2;j++){
    dl[4*j+0]=dv[j].x-lo; dl[4*j+1]=dv[j].y-lo; dl[4*j+2]=dv[j].z-lo; dl[4*j+3]=dv[j].w-lo;
    sl[4*j+0]=sv[j].x-lo; sl[4*j+1]=sv[j].y-lo; sl[4*j+2]=sv[j].z-lo; sl[4*j+3]=sv[j].w-lo;
  }
#pragma unroll
  for(int q=0;q<8;q++) atomicAdd(&h[dl[q]],1);
  __syncthreads();
  if(tid < NTILE){
    int ssum = 0;
    for(int i=0;i<256;i++) ssum += h[tid*256+i];
    hbase[tid] = atomicAdd(&bcur[g*NTILE+tid], ssum);  // same-XCD, 32/block
    hc[tid] = 0;
  }
  __syncthreads();
#pragma unroll
  for(int q=0;q<8;q++){
    int tt = dl[q] >> 8;
    int p = atomicAdd(&hc[tt],1) + hbase[tt];
    bpk[(size_t)(g*NTILE+tt)*BKT + p] = (sl[q]<<13) | dl[q];
  }
}

// ---- stage-1 bucket scatter, SELF-SUFFICIENT (derives cnt+rowptr from bcur
// prefix + own-bucket histogram; then scatters via LDS cursors).
__global__ __launch_bounds__(1024) void k_scatter_b(
    const int* __restrict__ bcur, const int* __restrict__ bpk,
    int* __restrict__ cnt, int* __restrict__ rowptr, int* __restrict__ eo){
  __shared__ int hist[256], cur[256];
  __shared__ int wsum[4];
  __shared__ int sbase;
  int tid = threadIdx.x;
  int g = blockIdx.x & 7, t = blockIdx.x >> 3;
  int lo = g*NPG1 + t*256;
  if(tid < 256) hist[tid] = 0;
  if(tid < 32){
    int v = bcur[g*NTILE + tid];
    int inc = v;
    for(int o=1;o<32;o<<=1){ int t2=__shfl_up(inc,o,64); if(tid>=o) inc+=t2; }
    if(tid == t) sbase = g*EPG1 + inc - v;   // exclusive prefix of tile totals
  }
  __syncthreads();
  int total = bcur[g*NTILE + t];
  int base = sbase;
  const int* bp = bpk + (size_t)(g*NTILE + t)*BKT;
  for(int i=tid; i<total; i+=1024)
    atomicAdd(&hist[(bp[i] & 8191) - t*256], 1);
  __syncthreads();
  int lane = tid & 63, w = tid >> 6;
  int v = 0, inc = 0;
  if(tid < 256){
    v = hist[tid]; inc = v;
    for(int o=1;o<64;o<<=1){ int t2=__shfl_up(inc,o,64); if(lane>=o) inc+=t2; }
    if(lane==63) wsum[w]=inc;
  }
  __syncthreads();
  if(tid < 256){
    int wb=0;
    for(int k=0;k<w;k++) wb+=wsum[k];
    int e = base + wb + inc - v;
    cnt[lo+tid] = v;
    rowptr[lo+tid] = e;
    cur[tid] = e;
  }
  __syncthreads();
  for(int i=tid; i<total; i+=1024){
    int pk = bp[i];
    int p = atomicAdd(&cur[(pk & 8191) - t*256], 1);
    eo[p] = g*NPG1 + (pk >> 13);
  }
}

// ---- R13 MERGED scan+scatter (stages 2/3): one block per graph (blockIdx=g
// -> XCD-affine). Scan cnt (1024-thr wave prefix) -> rowptr to global, running
// cursors stay in LDS; then scatter the graph's edges via LDS atomics (avg ~5
// hits/cursor). Replaces k_scan_w + k_scatter_r (2 dispatches -> 1); writes
// confined to the graph's esrc window (no write amplification, R4 lesson).
template<int PER>
__global__ __launch_bounds__(1024) void k_scan_scatter(
    const int* __restrict__ cnt, int R, int estride,
    int* __restrict__ rowptr,
    const int* __restrict__ se, const int* __restrict__ de,
    const int* __restrict__ gcnt, int reg, int* __restrict__ eo){
  __shared__ int wsum[16];
  __shared__ int curs[2464];     // max(KP1)=2458 cursors
  int g = blockIdx.x;
  int tid = threadIdx.x, lane = tid & 63, w = tid >> 6;
  int base = g*R;
  int i0 = tid*PER;
  int v[PER]; int s = 0;
#pragma unroll
  for(int j=0;j<PER;j++){ int i=i0+j; int x=(i<R)?cnt[base+i]:0; v[j]=s; s+=x; }
  int inc = s;
  for(int o=1;o<64;o<<=1){ int t=__shfl_up(inc,o,64); if(lane>=o) inc+=t; }
  if(lane==63) wsum[w]=inc;
  __syncthreads();
  int wb=0;
  for(int k=0;k<w;k++) wb+=wsum[k];
  int tb = g*estride + wb + inc - s;
#pragma unroll
  for(int j=0;j<PER;j++){
    int i=i0+j;
    if(i<R){
      int e = tb + v[j];
      rowptr[base+i] = e;
      curs[i] = e;
    }
  }
  __syncthreads();
  int m = gcnt[g]; if(m > reg) m = reg;
  const int* seg_ = se + (size_t)g*reg;
  const int* deg_ = de + (size_t)g*reg;
  for(int i=tid; i<m; i+=1024){
    int d = deg_[i];                       // global new node id
    int p = atomicAdd(&curs[d - base], 1); // LDS cursor
    eo[p] = seg_[i];
  }
}

// inorm normalize helper from accum stats
DI float inorm_of(const float* accum, int gc, float R, float x){
  float s = accum[gc*2], sq = accum[gc*2+1];
  float mu = s / R;
  float var = fmaxf(sq/R - mu*mu, 0.f);
  return eluf((x-mu)*rsqrtf(var+1e-5f));
}

// FUSED GAT v4: single-phase, latency-optimized, XCD-GRAPH-AFFINE.
// R6/R7: per-graph gather working set fits one XCD's 4MB L2 — grid = 8*bpg
// (padded), work = (b&7)*bpg + b/8 -> graph g runs entirely on XCD g under
// round-robin dispatch; gathers are XCD-L2 hits (441->420us confirmed).
template<int H,int F,int EB>
__global__ __launch_bounds__(256) void k_gat_fused(
    const float* __restrict__ xp, const float* __restrict__ als,
    const float* __restrict__ ald, const int* __restrict__ rowptr,
    const int* __restrict__ cnt, const int* __restrict__ esrc,
    const float* __restrict__ bias, float* __restrict__ out,
    float* __restrict__ accum, int RPG, int bpg){
  constexpr int C = H*F, C4 = C/4;
  constexpr int NPB = 256/C4;
  __shared__ float psum[4][C], psq[4][C];
  int tid = threadIdx.x;
  int nl = tid / C4, p = tid % C4;
  int work = (blockIdx.x & 7)*(gridDim.x >> 3) + (blockIdx.x >> 3);
  int g = work / bpg, t = work - g*bpg;
  int loc = t*NPB + nl;
  int node = g*RPG + loc;
  int hh = (4*p)/F;
  const float4* xp4 = (const float4*)xp;
  float4 r = make_float4(0.f,0.f,0.f,0.f);
  bool valid = loc < RPG;
  if(valid){
    float dvh = ald[node*H+hh];
    float sw  = expf(lrelu(als[node*H+hh] + dvh));   // self-loop weight
    float4 xs = xp4[(size_t)node*C4 + p];
    float den = sw;
    float ax=sw*xs.x, ay=sw*xs.y, az=sw*xs.z, aw_=sw*xs.w;
    int r0  = rowptr[node];
    int deg = cnt[node];
    for(int j=0; j<deg; j+=EB){
      int idx[EB]; float wv[EB]; float4 v[EB];
#pragma unroll
      for(int q=0;q<EB;q++)
        idx[q] = (j+q < deg) ? esrc[r0+j+q] : node;   // masked slots: safe dup
#pragma unroll
      for(int q=0;q<EB;q++)
        wv[q] = als[idx[q]*H+hh];
#pragma unroll
      for(int q=0;q<EB;q++)
        v[q] = xp4[(size_t)idx[q]*C4 + p];
#pragma unroll
      for(int q=0;q<EB;q++){
        float w = (j+q < deg) ? expf(lrelu(wv[q] + dvh)) : 0.f;
        den += w;
        ax += w*v[q].x; ay += w*v[q].y; az += w*v[q].z; aw_ += w*v[q].w;
      }
    }
    float inv = 1.f / den;
    float4 bv = ((const float4*)bias)[p];
    r.x=ax*inv+bv.x; r.y=ay*inv+bv.y; r.z=az*inv+bv.z; r.w=aw_*inv+bv.w;
    ((float4*)out)[(size_t)node*C4 + p] = r;
  }
  // ---- fused inorm stats (whole block belongs to graph g; invalid lanes r=0)
  float sx=r.x, sy=r.y, sz=r.z, sw2=r.w;
  float qx=r.x*r.x, qy=r.y*r.y, qz=r.z*r.z, qw=r.w*r.w;
#pragma unroll
  for(int off=C4; off<64; off<<=1){
    sx += __shfl_down(sx, off, 64); sy += __shfl_down(sy, off, 64);
    sz += __shfl_down(sz, off, 64); sw2 += __shfl_down(sw2, off, 64);
    qx += __shfl_down(qx, off, 64); qy += __shfl_down(qy, off, 64);
    qz += __shfl_down(qz, off, 64); qw += __shfl_down(qw, off, 64);
  }
  int lane = tid & 63, w = tid >> 6;
  if(lane < C4){
    psum[w][4*lane+0]=sx; psum[w][4*lane+1]=sy;
    psum[w][4*lane+2]=sz; psum[w][4*lane+3]=sw2;
    psq[w][4*lane+0]=qx;  psq[w][4*lane+1]=qy;
    psq[w][4*lane+2]=qz;  psq[w][4*lane+3]=qw;
  }
  __syncthreads();
  if(tid < C){
    float ts = psum[0][tid]+psum[1][tid]+psum[2][tid]+psum[3][tid];
    float tq = psq[0][tid]+psq[1][tid]+psq[2][tid]+psq[3][tid];
    atomicAdd(&accum[(g*C+tid)*2],   ts);
    atomicAdd(&accum[(g*C+tid)*2+1], tq);
  }
}

// R9 MERGED post-topk dispatch: blocks [0,ncomp) = edge compaction (reads
// newid), blocks [ncomp,..) = dense row-GEMM with fused pool-gather +
// deferred-inorm + attention-logit epilogue (reads oldid/scale). Both halves
// depend only on topk and are mutually independent -> compact hides under
// the longer gemm. LDS is a 16KB union. Compact g = blk&7 -> XCD-affine cnt.
template<int K,int CO,int NPG,int H,int CHUNK>
__global__ __launch_bounds__(256) void k_cpt_gemm(
    const int* __restrict__ se, const int* __restrict__ de,
    const int* __restrict__ gcnt_in, int fixed_in, int reg_in,
    const int* __restrict__ newid, int* __restrict__ gcnt_out,
    int* __restrict__ ons, int* __restrict__ ond, int reg_out,
    int* __restrict__ cnt, int ncomp,
    const float* __restrict__ X, const float* __restrict__ naccum, int nRPG,
    const int* __restrict__ oldid, const float* __restrict__ scale,
    const float* __restrict__ W, float* __restrict__ Y,
    const float* __restrict__ a_s, const float* __restrict__ a_d,
    float* __restrict__ als, float* __restrict__ ald, int n){
  constexpr int SUB = 256/CO;
  constexpr int NB = SUB*NPG;
  static_assert(NB*K <= 2*CHUNK, "xs must fit the union");
  __shared__ int sm[2*CHUNK];
  __shared__ int run, tbase;
  __shared__ float ps[4][NPG], pd[4][NPG];
  int tid = threadIdx.x;
  if((int)blockIdx.x < ncomp){
    // ---------------- compact half ----------------
    int* s_a = sm;
    int* s_b = sm + CHUNK;
    if(tid == 0) run = 0;
    __syncthreads();
    int blk = blockIdx.x;
    int g = blk & 7, t = blk >> 3;     // g == blockIdx%8 -> XCD-affine
    int mg = gcnt_in ? gcnt_in[g] : fixed_in;
    if(mg > reg_in) mg = reg_in;
    int base_l = t*CHUNK;
    if(base_l < mg){
      const int4* de4 = (const int4*)(de + (size_t)g*reg_in + base_l);
      const int4* se4 = (const int4*)(se + (size_t)g*reg_in + base_l);
      int4 BD[CHUNK/1024], BS[CHUNK/1024];
#pragma unroll
      for(int j=0;j<CHUNK/1024;j++){ BD[j]=de4[j*256+tid]; BS[j]=se4[j*256+tid]; }
      int cl = 0;
#pragma unroll
      for(int j=0;j<CHUNK/1024;j++){
        int eb = base_l + (j*256+tid)*4;
        int dd[4]={BD[j].x,BD[j].y,BD[j].z,BD[j].w};
        int ss[4]={BS[j].x,BS[j].y,BS[j].z,BS[j].w};
#pragma unroll
        for(int q=0;q<4;q++){
          if(eb+q < mg){
            int a = newid[ss[q]], b = newid[dd[q]];
            if(a>=0 && b>=0){ cl++; atomicAdd(&cnt[b], 1); }
          }
        }
      }
      int p0 = 0;
      if(cl) p0 = atomicAdd(&run, cl);
#pragma unroll
      for(int j=0;j<CHUNK/1024;j++){
        int eb = base_l + (j*256+tid)*4;
        int dd[4]={BD[j].x,BD[j].y,BD[j].z,BD[j].w};
        int ss[4]={BS[j].x,BS[j].y,BS[j].z,BS[j].w};
#pragma unroll
        for(int q=0;q<4;q++){
          if(eb+q < mg){
            int a = newid[ss[q]], b = newid[dd[q]];
            if(a>=0 && b>=0){ s_a[p0]=a; s_b[p0]=b; p0++; }
          }
        }
      }
    }
    __syncthreads();
    int ns = run;
    if(tid==0) tbase = ns ? atomicAdd(&gcnt_out[blockIdx.x & 7], ns) : 0;
    __syncthreads();
    int tb = tbase;
    int g2 = blockIdx.x & 7;
    for(int j=tid; j<ns; j+=256){
      int s2 = tb + j;
      if(s2 < reg_out){ ons[(size_t)g2*reg_out+s2]=s_a[j]; ond[(size_t)g2*reg_out+s2]=s_b[j]; }
    }
    return;
  }
  // ---------------- gemm half ----------------
  float (*xs)[K] = reinterpret_cast<float(*)[K]>(sm);
  int c = tid % CO, sg = tid / CO;
  int n0 = ((int)blockIdx.x - ncomp) * NB;
  for(int idx=tid; idx<NB*K; idx+=256){
    int r = idx / K, k = idx % K;
    int row = n0 + r;
    float v = 0.f;
    if(row < n){
      int orow = oldid[row];
      int og = orow / nRPG;
      v = inorm_of(naccum, og*K + k, (float)nRPG, X[(size_t)orow*K + k]) * scale[row];
    }
    xs[r][k] = v;
  }
  __syncthreads();
  float acc[NPG];
#pragma unroll
  for(int q=0;q<NPG;q++) acc[q]=0.f;
  for(int k=0;k<K;k++){
    float wv = W[(size_t)k*CO + c];
#pragma unroll
    for(int q=0;q<NPG;q++) acc[q] += xs[sg*NPG+q][k]*wv;
  }
  float asc = a_s[c], adc = a_d[c];
  float vs[NPG], vd[NPG];
#pragma unroll
  for(int q=0;q<NPG;q++){
    int row = n0 + sg*NPG + q;
    if(row < n) Y[(size_t)row*CO + c] = acc[q];
    vs[q] = acc[q]*asc; vd[q] = acc[q]*adc;
  }
#pragma unroll
  for(int o=32;o>0;o>>=1){
#pragma unroll
    for(int q=0;q<NPG;q++){
      vs[q] += __shfl_down(vs[q], o, 64);
      vd[q] += __shfl_down(vd[q], o, 64);
    }
  }
  int lane = tid & 63, w = tid >> 6;
  if(H == 2){
    if(lane == 0){
      int sg_ = w >> 1, h = w & 1;
#pragma unroll
      for(int q=0;q<NPG;q++){
        int row = n0 + sg_*NPG + q;
        if(row < n){ als[row*2+h] = vs[q]; ald[row*2+h] = vd[q]; }
      }
    }
  } else {
    if(lane == 0){
#pragma unroll
      for(int q=0;q<NPG;q++){ ps[w][q]=vs[q]; pd[w][q]=vd[q]; }
    }
    __syncthreads();
    if(tid < NPG){
      float s=0.f, d=0.f;
      for(int ww=0;ww<4;ww++){ s+=ps[ww][tid]; d+=pd[ww][tid]; }
      int row = n0 + tid;
      if(row < n){ als[row]=s; ald[row]=d; }
    }
  }
}

// fused inorm + ELU + pool score + orderable key (stages 1/2). SCORE-ONLY.
// R10: shuffle reduction — C=32 rows live in a 32-lane subgroup (zero
// barriers); C=128 rows span 2 waves (1 barrier).
template<int C>
__global__ __launch_bounds__(256) void k_inorm_score(
    const float* __restrict__ x, const float* __restrict__ accum,
    const float* __restrict__ p, int R, int total,
    float* __restrict__ score, unsigned* __restrict__ u){
  int tid = threadIdx.x;
  int i = blockIdx.x*256 + tid;
  int c = tid & (C-1);
  bool act = i < total;
  float v = 0.f, pv = 0.f;
  if(act){
    int g = i / (R*C);
    v = inorm_of(accum, g*C+c, (float)R, x[i]);
    pv = p[c];
  }
  float vp = v*pv, pp = pv*pv;
  if(C <= 64){
#pragma unroll
    for(int o=C/2;o>0;o>>=1){
      vp += __shfl_down(vp, o, C);
      pp += __shfl_down(pp, o, C);
    }
    if(act && c==0){
      float sv = tanhf(vp*rsqrtf(pp));
      int row = i / C;
      score[row] = sv;
      unsigned bts = __float_as_uint(sv);
      u[row] = (bts & 0x80000000u) ? ~bts : (bts | 0x80000000u);
    }
  } else {
    __shared__ float sv_[4], sp_[4];
#pragma unroll
    for(int o=32;o>0;o>>=1){
      vp += __shfl_down(vp, o, 64);
      pp += __shfl_down(pp, o, 64);
    }
    int lane = tid & 63, w = tid >> 6;
    if(lane==0){ sv_[w]=vp; sp_[w]=pp; }
    __syncthreads();
    if(act && c==0){   // c==0 -> lane0 of waves 0 and 2 (row spans w, w+1)
      float tv = sv_[w]+sv_[w+1], tp = sp_[w]+sp_[w+1];
      float sv = tanhf(tv*rsqrtf(tp));
      int row = i / C;
      score[row] = sv;
      unsigned bts = __float_as_uint(sv);
      u[row] = (bts & 0x80000000u) ? ~bts : (bts | 0x80000000u);
    }
  }
}

// MERGED top-k: radix select (exact k-th + ties) THEN deterministic
// compaction, one block per graph.
__global__ __launch_bounds__(1024) void k_topk(
    const unsigned* __restrict__ u, const float* __restrict__ score,
    int R, int Ksel, int* __restrict__ newid, int* __restrict__ oldid,
    float* __restrict__ scale){
  __shared__ int hist[2048];
  __shared__ int seg[32];
  __shared__ int sh_b, sh_k;
  __shared__ int wsA[16], wsB[16];
  __shared__ int carr0, carr1;
  int g = blockIdx.x, tid = threadIdx.x, lane = tid&63, w = tid>>6;
  const unsigned* ug = u + (size_t)g*R;
  // ---- phase 1: select
  unsigned prefix = 0;
  int K = Ksel;
  for(int lev=0; lev<3; lev++){
    int shf = (lev==0)?21:((lev==1)?10:0);
    int nb  = (lev==2)?1024:2048;
    for(int i=tid;i<2048;i+=1024) hist[i]=0;
    __syncthreads();
    for(int i=tid;i<R;i+=1024){
      unsigned v = ug[i];
      bool ok = (lev==0) || (lev==1 && (v>>21)==prefix) || (lev==2 && (v>>10)==prefix);
      if(ok) atomicAdd(&hist[(v>>shf)&(nb-1)], 1);
    }
    __syncthreads();
    int W = nb/32;
    if(tid<32){ int s=0; int lo=nb-W*(tid+1); for(int b=lo;b<lo+W;b++) s+=hist[b]; seg[tid]=s; }
    __syncthreads();
    if(tid==0){
      int kk=K, sgi=0;
      while(seg[sgi]<kk){ kk-=seg[sgi]; sgi++; }
      int b = nb-1-W*sgi;
      while(hist[b]<kk){ kk-=hist[b]; b--; }
      sh_b=b; sh_k=kk;
    }
    __syncthreads();
    int b = sh_b; K = sh_k;
    if(lev==0) prefix = (unsigned)b;
    else if(lev==1) prefix = (prefix<<11) | (unsigned)b;
    else prefix = (prefix<<10) | (unsigned)b;
    __syncthreads();
  }
  unsigned thr = prefix;
  int need = K;
  // ---- phase 2: compact (u>thr plus lowest-index u==thr; lax.top_k ties)
  if(tid==0){ carr0=0; carr1=0; }
  __syncthreads();
  for(int bb=0; bb<R; bb+=1024){
    int i = bb + tid; bool in = i < R;
    unsigned uv = in ? ug[i] : 0u;
    int eq = (in && uv==thr) ? 1:0;
    int gt = (in && uv>thr) ? 1:0;
    int inc = eq;
    for(int o=1;o<64;o<<=1){ int t=__shfl_up(inc,o,64); if(lane>=o) inc+=t; }
    if(lane==63) wsA[w]=inc;
    __syncthreads();
    int wb=0; for(int k=0;k<w;k++) wb+=wsA[k];
    int eq_excl = carr0 + wb + inc - eq;
    int take = (gt || (eq && eq_excl<need)) ? 1 : 0;
    int inc2 = take;
    for(int o=1;o<64;o<<=1){ int t=__shfl_up(inc2,o,64); if(lane>=o) inc2+=t; }
    if(lane==63) wsB[w]=inc2;
    __syncthreads();
    int wb2=0; for(int k=0;k<w;k++) wb2+=wsB[k];
    int pos = carr1 + wb2 + inc2 - take;
    if(take){
      int nr = g*Ksel + pos;
      newid[(size_t)g*R+i] = nr;
      oldid[nr] = g*R+i;
      scale[nr] = score[(size_t)g*R+i];
    }
    __syncthreads();
    if(tid==1023){ carr0 += wb + inc; carr1 += wb2 + inc2; }
    __syncthreads();
  }
}

// fused gate pipeline with stage-3 inorm on input, 8 rows/block:
// each 64-lane group computes TWO rows sharing one gw1 stream.
__global__ __launch_bounds__(256) void k_gate_fused(
    const float* __restrict__ X, const float* __restrict__ accum,
    const float* __restrict__ gw1, const float* __restrict__ gb1,
    const float* __restrict__ gw2, const float* __restrict__ gb2,
    float* __restrict__ gatev, int n){
  __shared__ float xs[8][256];
  int tid = threadIdx.x;
  int n0 = blockIdx.x*8;
  for(int idx=tid; idx<2048; idx+=256){
    int r = idx >> 8, k = idx & 255;
    int row = n0 + r;
    float v = 0.f;
    if(row < n){
      int g = row / KP2;
      v = inorm_of(accum, g*256+k, (float)KP2, X[(size_t)row*256 + k]);
    }
    xs[r][k] = v;
  }
  __syncthreads();
  int sg = tid >> 6, c = tid & 63;
  float a0 = 0.f, a1 = 0.f;
#pragma unroll 8
  for(int k=0;k<256;k++){
    float w = gw1[k*64+c];
    a0 = fmaf(xs[sg][k],   w, a0);
    a1 = fmaf(xs[sg+4][k], w, a1);
  }
  float gb = gb1[c], g2 = gw2[c];
  float v0 = eluf(a0 + gb) * g2;
  float v1 = eluf(a1 + gb) * g2;
#pragma unroll
  for(int o=32;o>0;o>>=1){
    v0 += __shfl_down(v0, o, 64);
    v1 += __shfl_down(v1, o, 64);
  }
  if(c==0){
    int r0 = n0 + sg, r1 = n0 + sg + 4;
    if(r0 < n) gatev[r0] = v0 + gb2[0];
    if(r1 < n) gatev[r1] = v1 + gb2[0];
  }
}

// MERGED h-GEMM + attention accumulate; 8 rows/block halves the aw stream.
__global__ __launch_bounds__(256) void k_attn_gemm(
    const float* __restrict__ X, const float* __restrict__ accum,
    const float* __restrict__ W, const float* __restrict__ bias,
    const float* __restrict__ gatev, float* __restrict__ gvec){
  __shared__ float xs[8][256];
  __shared__ float red[256];
  int tid = threadIdx.x;
  int t = blockIdx.x, g = blockIdx.y;
  int r0 = t*8;
  float mx = -1e30f;
  for(int r=tid;r<KP2;r+=256) mx = fmaxf(mx, gatev[g*KP2+r]);
  red[tid]=mx; __syncthreads();
  for(int s=128;s>0;s>>=1){ if(tid<s) red[tid]=fmaxf(red[tid],red[tid+s]); __syncthreads(); }
  mx = red[0]; __syncthreads();
  float sm=0.f;
  for(int r=tid;r<KP2;r+=256) sm += expf(gatev[g*KP2+r]-mx);
  red[tid]=sm; __syncthreads();
  for(int s=128;s>0;s>>=1){ if(tid<s) red[tid]+=red[tid+s]; __syncthreads(); }
  float inv = 1.f/red[0];
  __syncthreads();
  for(int idx=tid; idx<2048; idx+=256){
    int r = idx >> 8, k = idx & 255;
    int lr = r0 + r;
    float v = 0.f;
    if(lr < KP2){
      int row = g*KP2 + lr;
      v = inorm_of(accum, g*256+k, (float)KP2, X[(size_t)row*256 + k]);
    }
    xs[r][k] = v;
  }
  __syncthreads();
  int c = tid;
  float acc[8];
#pragma unroll
  for(int q=0;q<8;q++) acc[q]=0.f;
  for(int k=0;k<256;k++){
    float wv = W[(size_t)k*256 + c];
#pragma unroll
    for(int q=0;q<8;q++) acc[q] += xs[q][k]*wv;
  }
  float bv = bias[c];
  float tot = 0.f;
#pragma unroll
  for(int q=0;q<8;q++){
    int lr = r0 + q;
    if(lr < KP2){
      float h = eluf(acc[q] + bv);
      tot += expf(gatev[g*KP2+lr]-mx) * h;
    }
  }
  atomicAdd(&gvec[g*256+c], tot*inv);
}

// tiny-n tail MLP: compile-time K fully pipelined (R13/R2-confirmed: keep
// split — the 8-block merged tail regressed to 60+us latency-serialized
// weight streams, OccupancyPercent 0.33%)
template<int K,int CO,int ACT>
__global__ __launch_bounds__(256) void k_mlp_t(
    const float* __restrict__ X, const float* __restrict__ W,
    const float* __restrict__ b, float* __restrict__ Y, int n){
  int i = blockIdx.x*256+threadIdx.x;
  if(i>=n*CO) return;
  int r=i/CO, c=i%CO;
  const float* xr = X + (size_t)r*K;
  float a=0.f;
#pragma unroll 16
  for(int k=0;k<K;k++) a = fmaf(xr[k], W[(size_t)k*CO+c], a);
  a += b[c];
  if(ACT) a = eluf(a);
  Y[i]=a;
}

__global__ __launch_bounds__(64) void k_head(
    const float* __restrict__ z2, const float* __restrict__ w3,
    const float* __restrict__ b3, float* __restrict__ out){
  __shared__ float zc[10]; __shared__ float mred, sred;
  int g=blockIdx.x, tid=threadIdx.x;
  if(tid<10){
    float a=0.f;
#pragma unroll 16
    for(int k=0;k<128;k++) a += z2[g*128+k]*w3[k*10+tid];
    zc[tid]=a+b3[tid];
  }
  __syncthreads();
  if(tid==0){
    float m=zc[0];
    for(int k=1;k<10;k++) m=fmaxf(m,zc[k]);
    float s=0.f;
    for(int k=0;k<10;k++) s+=expf(zc[k]-m);
    mred=m; sred=logf(s);
  }
  __syncthreads();
  if(tid<10) out[g*10+tid]=zc[tid]-mred-sred;
}

} // namespace pk

extern "C" void kernel_launch(void* const* d_in, const int* in_sizes, int n_in,
                              void* d_out, int out_size, void* d_ws, size_t ws_size,
                              hipStream_t stream){
  using namespace pk;
  (void)in_sizes; (void)n_in; (void)out_size;
  const float* pos = (const float*)d_in[0];
  const int*   src = (const int*)d_in[1];
  const int*   dst = (const int*)d_in[2];
  const float* W1  = (const float*)d_in[3];
  const float* as1 = (const float*)d_in[4];
  const float* ad1 = (const float*)d_in[5];
  const float* b1  = (const float*)d_in[6];
  const float* p1  = (const float*)d_in[7];
  const float* W2  = (const float*)d_in[8];
  const float* as2 = (const float*)d_in[9];
  const float* ad2 = (const float*)d_in[10];
  const float* b2  = (const float*)d_in[11];
  const float* p2  = (const float*)d_in[12];
  const float* W3  = (const float*)d_in[13];
  const float* as3 = (const float*)d_in[14];
  const float* ad3 = (const float*)d_in[15];
  const float* b3  = (const float*)d_in[16];
  const float* gw1 = (const float*)d_in[17];
  const float* gb1 = (const float*)d_in[18];
  const float* gw2 = (const float*)d_in[19];
  const float* gb2 = (const float*)d_in[20];
  const float* aw  = (const float*)d_in[21];
  const float* ab  = (const float*)d_in[22];
  const float* w1  = (const float*)d_in[23];
  const float* bb1 = (const float*)d_in[24];
  const float* w2  = (const float*)d_in[25];
  const float* bb2 = (const float*)d_in[26];
  const float* w3  = (const float*)d_in[27];
  const float* bb3 = (const float*)d_in[28];
  float* out = (float*)d_out;

  char* base = (char*)d_ws; size_t off = 0;
  auto alloc = [&](size_t nbytes)->char*{
    char* p = base + off; off = (off + nbytes + 255) & ~(size_t)255; return p;
  };
  // --- zero-init region (one memset) ---
  int*   cnt2  = (int*)alloc((size_t)NN2*4);
  int*   cnt3  = (int*)alloc((size_t)NN3*4);
  int*   ecnt2 = (int*)alloc((size_t)BG*4);
  int*   ecnt3 = (int*)alloc((size_t)BG*4);
  float* acc1  = (float*)alloc((size_t)BG*32*2*4);
  float* acc2  = (float*)alloc((size_t)BG*128*2*4);
  float* acc3  = (float*)alloc((size_t)BG*256*2*4);
  float* gvec  = (float*)alloc((size_t)BG*256*4);
  int*   bcur1 = (int*)alloc((size_t)BG*NTILE*4);
  size_t zend = off;
  // --- 0xFF-init region (newid = -1, one memset) ---
  int*   newid1 = (int*)alloc((size_t)NB1*4);
  int*   newid2 = (int*)alloc((size_t)NN2*4);
  size_t fstart = (size_t)((char*)newid1 - base);
  size_t fend = off;
  // --- plain scratch ---
  int*      cnt1   = (int*)alloc((size_t)NB1*4);           // dense-written
  int*      bpk1   = (int*)alloc((size_t)BG*NTILE*BKT*4);  // bucket-packed edges
  float*    xp1    = (float*)alloc((size_t)NB1*32*4);
  float*    als1   = (float*)alloc((size_t)NB1*2*4);
  float*    ald1   = (float*)alloc((size_t)NB1*2*4);
  int*      rowptr1= (int*)alloc((size_t)NB1*4);
  int*      esrc1  = (int*)alloc((size_t)NE*4);
  float*    out1   = (float*)alloc((size_t)NB1*32*4);
  float*    score1 = (float*)alloc((size_t)NB1*4);
  unsigned* u1     = (unsigned*)alloc((size_t)NB1*4);
  int*      oldid1 = (int*)alloc((size_t)NN2*4);
  float*    scale1 = (float*)alloc((size_t)NN2*4);
  int*      ns2    = (int*)alloc((size_t)CAP2*4);
  int*      nd2    = (int*)alloc((size_t)CAP2*4);
  int*      rowptr2= (int*)alloc((size_t)NN2*4);
  int*      esrc2  = (int*)alloc((size_t)CAP2*4);
  float*    xp2    = (float*)alloc((size_t)NN2*128*4);
  float*    als2   = (float*)alloc((size_t)NN2*2*4);
  float*    ald2   = (float*)alloc((size_t)NN2*2*4);
  float*    out2   = (float*)alloc((size_t)NN2*128*4);
  float*    score2 = (float*)alloc((size_t)NN2*4);
  unsigned* u2     = (unsigned*)alloc((size_t)NN2*4);
  int*      oldid2 = (int*)alloc((size_t)NN3*4);
  float*    scale2 = (float*)alloc((size_t)NN3*4);
  int*      ns3    = (int*)alloc((size_t)CAP3*4);
  int*      nd3    = (int*)alloc((size_t)CAP3*4);
  int*      rowptr3= (int*)alloc((size_t)NN3*4);
  int*      esrc3  = (int*)alloc((size_t)CAP3*4);
  float*    xp3    = (float*)alloc((size_t)NN3*256*4);
  float*    als3   = (float*)alloc((size_t)NN3*4);
  float*    ald3   = (float*)alloc((size_t)NN3*4);
  float*    out3   = (float*)alloc((size_t)NN3*256*4);
  float*    gatev  = (float*)alloc((size_t)NN3*4);
  float*    z1     = (float*)alloc((size_t)BG*512*4);
  float*    z2     = (float*)alloc((size_t)BG*128*4);
  if(off > ws_size) return;  // workspace too small: fail visibly

  auto cdiv = [](int a, int b){ return (a+b-1)/b; };

  hipMemsetAsync(base, 0, zend, stream);
  hipMemsetAsync(base + fstart, 0xFF, fend - fstart, stream);

  // ---------------- stage 1: GAT(3->32, H=2,F=16) ----------------
  k_s1_front<<<192,1024,0,stream>>>(pos,W1,as1,ad1,xp1,als1,ald1,src,dst,bcur1,bpk1);
  k_scatter_b<<<256,1024,0,stream>>>(bcur1,bpk1,cnt1,rowptr1,esrc1);
  k_gat_fused<2,16,16><<<2048,256,0,stream>>>(xp1,als1,ald1,rowptr1,cnt1,esrc1,b1,out1,acc1,NPG1,256);
  k_inorm_score<32><<<cdiv(NB1*32,256),256,0,stream>>>(out1,acc1,p1,8192,NB1*32,score1,u1);
  // ---------------- pool 1 (k=2458) ----------------
  k_topk<<<BG,1024,0,stream>>>(u1,score1,8192,KP1,newid1,oldid1,scale1);
  // merged: compact (512 blocks, chunk 2048) + stage-2 gemm (2458 blocks)
  k_cpt_gemm<32,128,4,2,2048><<<512+cdiv(NN2,8),256,0,stream>>>(
      src,dst,nullptr,EPG1,EPG1,newid1,ecnt2,ns2,nd2,REG2,cnt2,512,
      out1,acc1,NPG1,oldid1,scale1,W2,xp2,as2,ad2,als2,ald2,NN2);
  // merged scan+scatter (LDS cursors), one block per graph
  k_scan_scatter<3><<<BG,1024,0,stream>>>(cnt2,KP1,REG2,rowptr2,ns2,nd2,ecnt2,REG2,esrc2);
  // bpg = ceil(2458/8)=308 -> grid 2464, graph g pinned to XCD g
  k_gat_fused<2,64,8><<<8*308,256,0,stream>>>(xp2,als2,ald2,rowptr2,cnt2,esrc2,b2,out2,acc2,KP1,308);
  k_inorm_score<128><<<cdiv(NN2*128,256),256,0,stream>>>(out2,acc2,p2,KP1,NN2*128,score2,u2);
  // ---------------- pool 2 (k=738) ----------------
  k_topk<<<BG,1024,0,stream>>>(u2,score2,KP1,KP2,newid2,oldid2,scale2);
  // merged: compact (64 blocks, chunk 2048) + stage-3 gemm (1476 blocks)
  k_cpt_gemm<128,256,4,1,2048><<<64+cdiv(NN3,4),256,0,stream>>>(
      ns2,nd2,ecnt2,0,REG2,newid2,ecnt3,ns3,nd3,REG3,cnt3,64,
      out2,acc2,KP1,oldid2,scale2,W3,xp3,as3,ad3,als3,ald3,NN3);
  k_scan_scatter<1><<<BG,1024,0,stream>>>(cnt3,KP2,REG3,rowptr3,ns3,nd3,ecnt3,REG3,esrc3);
  // bpg=185 blocks/graph, grid 1480, graph g pinned to XCD g
  k_gat_fused<1,256,4><<<8*185,256,0,stream>>>(xp3,als3,ald3,rowptr3,cnt3,esrc3,b3,out3,acc3,KP2,185);
  // ---------------- global attention + MLP head (stage-3 norm fused in) ----
  k_gate_fused<<<cdiv(NN3,8),256,0,stream>>>(out3,acc3,gw1,gb1,gw2,gb2,gatev,NN3);
  k_attn_gemm<<<dim3(cdiv(KP2,8),BG),256,0,stream>>>(out3,acc3,aw,ab,gatev,gvec);
  k_mlp_t<256,512,1><<<cdiv(BG*512,256),256,0,stream>>>(gvec,w1,bb1,z1,BG);
  k_mlp_t<512,128,1><<<cdiv(BG*128,256),256,0,stream>>>(z1,w2,bb2,z2,BG);
  k_head<<<BG,64,0,stream>>>(z2,w3,bb3,out);
}

// Round 14
// 389.635 us; speedup vs baseline: 1.0140x; 1.0140x over previous
//
#include <hip/hip_runtime.h>
#include <cstdint>
#include <cstddef>

#define DI __device__ __forceinline__

namespace pk {

constexpr int NB1 = 65536;      // stage-1 nodes (B*N)
constexpr int NE  = 1048576;    // edges (B*N*DEG)
constexpr int BG  = 8;          // graphs
constexpr int NPG1 = 8192;      // nodes per graph, stage 1
constexpr int EPG1 = NE/BG;     // edges per graph, stage 1 (131072)
constexpr int KP1 = 2458;       // top-k 1
constexpr int KP2 = 738;        // top-k 2
constexpr int NN2 = BG*KP1;     // 19664
constexpr int NN3 = BG*KP2;     // 5904
constexpr int REG2 = 16384;     // per-graph edge region after pool1 (exp 11.8K±0.1K)
constexpr int REG3 = 4096;      // per-graph edge region after pool2 (exp ~1.1K)
constexpr int CAP2 = BG*REG2;
constexpr int CAP3 = BG*REG3;
constexpr int CPB1 = 16;        // count blocks per graph
constexpr int NTILE = 32;      // 256-node tiles per graph (8192/256)
constexpr int BKT = 5120;       // bucket capacity per (graph,tile): mean 4096 + 16 sigma

// R11 PITFALL (recorded): hipLaunchCooperativeKernel under this harness's
// graph capture produced WRONG RESULTS with phase logic line-identical to the
// passing split kernels. Cooperative grid.sync is NOT usable here.
// R13 PITFALL (recorded): merging scan+scatter cost stage-2 its 512-block
// scatter parallelism (8 blocks x dependent chains > 1 saved dispatch gap).
// Merge is kept ONLY for stage-3 (~8.8K edges, parallelism-neutral).

DI float lrelu(float x){ return x > 0.f ? x : 0.2f*x; }
DI float eluf(float x){ return x > 0.f ? x : expf(x) - 1.f; }

// XCD-affinity swizzle (heuristic only).
DI int swz_block(){
  int nb = gridDim.x, b = blockIdx.x;
  if((nb & 7) == 0) return (b & 7)*(nb >> 3) + (b >> 3);
  return b;
}

// ---- MERGED stage-1 front: blocks [0,64) = pos@W1 projection (+logits),
// blocks [64,192) = TILE-BUCKET partition (counting sort phase A).
// R4/R5 lessons: no cross-XCD fine-grained atomics, no random 4B scatters.
__global__ __launch_bounds__(1024) void k_s1_front(
    const float* __restrict__ pos, const float* __restrict__ W,
    const float* __restrict__ as_, const float* __restrict__ ad_,
    float* __restrict__ xp, float* __restrict__ als, float* __restrict__ ald,
    const int* __restrict__ se, const int* __restrict__ de,
    int* __restrict__ bcur, int* __restrict__ bpk){
  __shared__ int h[NPG1];
  __shared__ int hbase[NTILE];
  __shared__ int hc[NTILE];
  int tid = threadIdx.x;
  if(blockIdx.x < 64){
    // ---- projection part (NB1 = 64*1024 exactly)
    int i = blockIdx.x*1024 + tid;
    float p0=pos[3*i], p1=pos[3*i+1], p2=pos[3*i+2];
    float row[32];
#pragma unroll
    for(int c=0;c<32;c++) row[c] = p0*W[c] + p1*W[32+c] + p2*W[64+c];
    float s0=0.f,d0=0.f,s1=0.f,d1=0.f;
#pragma unroll
    for(int f=0;f<16;f++){
      s0 += row[f]*as_[f];        d0 += row[f]*ad_[f];
      s1 += row[16+f]*as_[16+f];  d1 += row[16+f]*ad_[16+f];
    }
    float4* o = reinterpret_cast<float4*>(xp + (size_t)i*32);
#pragma unroll
    for(int q=0;q<8;q++) o[q] = make_float4(row[4*q],row[4*q+1],row[4*q+2],row[4*q+3]);
    ((float2*)als)[i] = make_float2(s0,s1);
    ((float2*)ald)[i] = make_float2(d0,d1);
    return;
  }
  // ---- bucket partition: 128 blocks = 8 graphs (b&7 -> XCD-affine) x 16 chunks
  int bb = blockIdx.x - 64;
  int g = bb & 7, t = bb >> 3;
  for(int i=tid;i<NPG1;i+=1024) h[i]=0;
  __syncthreads();
  const int4* de4 = (const int4*)(de + g*EPG1 + t*(EPG1/CPB1));
  const int4* se4 = (const int4*)(se + g*EPG1 + t*(EPG1/CPB1));
  int lo = g*NPG1;
  int4 dv[2], sv[2];
#pragma unroll
  for(int j=0;j<2;j++){ dv[j]=de4[j*1024+tid]; sv[j]=se4[j*1024+tid]; }
  int dl[8], sl[8];
#pragma unroll
  for(int j=0;j<2;j++){
    dl[4*j+0]=dv[j].x-lo; dl[4*j+1]=dv[j].y-lo; dl[4*j+2]=dv[j].z-lo; dl[4*j+3]=dv[j].w-lo;
    sl[4*j+0]=sv[j].x-lo; sl[4*j+1]=sv[j].y-lo; sl[4*j+2]=sv[j].z-lo; sl[4*j+3]=sv[j].w-lo;
  }
#pragma unroll
  for(int q=0;q<8;q++) atomicAdd(&h[dl[q]],1);
  __syncthreads();
  if(tid < NTILE){
    int ssum = 0;
    for(int i=0;i<256;i++) ssum += h[tid*256+i];
    hbase[tid] = atomicAdd(&bcur[g*NTILE+tid], ssum);  // same-XCD, 32/block
    hc[tid] = 0;
  }
  __syncthreads();
#pragma unroll
  for(int q=0;q<8;q++){
    int tt = dl[q] >> 8;
    int p = atomicAdd(&hc[tt],1) + hbase[tt];
    bpk[(size_t)(g*NTILE+tt)*BKT + p] = (sl[q]<<13) | dl[q];
  }
}

// ---- stage-1 bucket scatter, SELF-SUFFICIENT (derives cnt+rowptr from bcur
// prefix + own-bucket histogram; then scatters via LDS cursors).
__global__ __launch_bounds__(1024) void k_scatter_b(
    const int* __restrict__ bcur, const int* __restrict__ bpk,
    int* __restrict__ cnt, int* __restrict__ rowptr, int* __restrict__ eo){
  __shared__ int hist[256], cur[256];
  __shared__ int wsum[4];
  __shared__ int sbase;
  int tid = threadIdx.x;
  int g = blockIdx.x & 7, t = blockIdx.x >> 3;
  int lo = g*NPG1 + t*256;
  if(tid < 256) hist[tid] = 0;
  if(tid < 32){
    int v = bcur[g*NTILE + tid];
    int inc = v;
    for(int o=1;o<32;o<<=1){ int t2=__shfl_up(inc,o,64); if(tid>=o) inc+=t2; }
    if(tid == t) sbase = g*EPG1 + inc - v;   // exclusive prefix of tile totals
  }
  __syncthreads();
  int total = bcur[g*NTILE + t];
  int base = sbase;
  const int* bp = bpk + (size_t)(g*NTILE + t)*BKT;
  for(int i=tid; i<total; i+=1024)
    atomicAdd(&hist[(bp[i] & 8191) - t*256], 1);
  __syncthreads();
  int lane = tid & 63, w = tid >> 6;
  int v = 0, inc = 0;
  if(tid < 256){
    v = hist[tid]; inc = v;
    for(int o=1;o<64;o<<=1){ int t2=__shfl_up(inc,o,64); if(lane>=o) inc+=t2; }
    if(lane==63) wsum[w]=inc;
  }
  __syncthreads();
  if(tid < 256){
    int wb=0;
    for(int k=0;k<w;k++) wb+=wsum[k];
    int e = base + wb + inc - v;
    cnt[lo+tid] = v;
    rowptr[lo+tid] = e;
    cur[tid] = e;
  }
  __syncthreads();
  for(int i=tid; i<total; i+=1024){
    int pk = bp[i];
    int p = atomicAdd(&cur[(pk & 8191) - t*256], 1);
    eo[p] = g*NPG1 + (pk >> 13);
  }
}

// per-graph-region atomic scatter (stage 2; 512 blocks — R13 lesson: keep
// the wide scatter, parallelism > dispatch-gap saving at 94K edges)
__global__ __launch_bounds__(256) void k_scatter_r(
    const int* __restrict__ se, const int* __restrict__ de,
    const int* __restrict__ gcnt, int reg,
    int* __restrict__ cursor, int* __restrict__ eo){
  int i = swz_block()*256 + threadIdx.x;
  int g = i / reg, loc = i % reg;
  if(loc < gcnt[g]){
    int p = atomicAdd(&cursor[de[i]], 1);
    eo[p] = se[i];
  }
}

// 256-thread per-graph scan, compile-time PER (keeps v[] in registers).
template<int PER>
DI void scan256(const int* __restrict__ cnt, int R, int estride,
                int* __restrict__ rowptr, int* __restrict__ cursor, int g){
  __shared__ int wsum[4];
  int tid = threadIdx.x, lane = tid & 63, w = tid >> 6;
  int base = g*R;
  int i0 = tid*PER;
  int v[PER]; int s = 0;
#pragma unroll
  for(int j=0;j<PER;j++){ int i=i0+j; int x=(i<R)?cnt[base+i]:0; v[j]=s; s+=x; }
  int inc = s;
  for(int o=1;o<64;o<<=1){ int t=__shfl_up(inc,o,64); if(lane>=o) inc+=t; }
  if(lane==63) wsum[w]=inc;
  __syncthreads();
  int wb=0;
  for(int k=0;k<w;k++) wb+=wsum[k];
  int tb = g*estride + wb + inc - s;
#pragma unroll
  for(int j=0;j<PER;j++){
    int i=i0+j;
    if(i<R){
      int e=tb+v[j];
      rowptr[base+i]=e;
      cursor[base+i]=e;
    }
  }
}

// standalone 8-block scan wrapper (stage 2)
template<int PER>
__global__ __launch_bounds__(256) void k_scan_w(
    const int* __restrict__ cnt, int R, int estride,
    int* __restrict__ rowptr, int* __restrict__ cursor){
  scan256<PER>(cnt, R, estride, rowptr, cursor, (int)blockIdx.x);
}

// ---- stage-3 MERGED scan+scatter: one block per graph (blockIdx=g ->
// XCD-affine). ~8.8K edges over 8x1024 threads = ~1 edge/thread, so the
// parallelism loss is nil (unlike stage 2 — R13 lesson). LDS cursors.
template<int PER>
__global__ __launch_bounds__(1024) void k_scan_scatter(
    const int* __restrict__ cnt, int R, int estride,
    int* __restrict__ rowptr,
    const int* __restrict__ se, const int* __restrict__ de,
    const int* __restrict__ gcnt, int reg, int* __restrict__ eo){
  __shared__ int wsum[16];
  __shared__ int curs[1024];     // KP2=738 cursors
  int g = blockIdx.x;
  int tid = threadIdx.x, lane = tid & 63, w = tid >> 6;
  int base = g*R;
  int i0 = tid*PER;
  int v[PER]; int s = 0;
#pragma unroll
  for(int j=0;j<PER;j++){ int i=i0+j; int x=(i<R)?cnt[base+i]:0; v[j]=s; s+=x; }
  int inc = s;
  for(int o=1;o<64;o<<=1){ int t=__shfl_up(inc,o,64); if(lane>=o) inc+=t; }
  if(lane==63) wsum[w]=inc;
  __syncthreads();
  int wb=0;
  for(int k=0;k<w;k++) wb+=wsum[k];
  int tb = g*estride + wb + inc - s;
#pragma unroll
  for(int j=0;j<PER;j++){
    int i=i0+j;
    if(i<R){
      int e = tb + v[j];
      rowptr[base+i] = e;
      curs[i] = e;
    }
  }
  __syncthreads();
  int m = gcnt[g]; if(m > reg) m = reg;
  const int* seg_ = se + (size_t)g*reg;
  const int* deg_ = de + (size_t)g*reg;
  for(int i=tid; i<m; i+=1024){
    int d = deg_[i];                       // global new node id
    int p = atomicAdd(&curs[d - base], 1); // LDS cursor
    eo[p] = seg_[i];
  }
}

// inorm normalize helper from accum stats
DI float inorm_of(const float* accum, int gc, float R, float x){
  float s = accum[gc*2], sq = accum[gc*2+1];
  float mu = s / R;
  float var = fmaxf(sq/R - mu*mu, 0.f);
  return eluf((x-mu)*rsqrtf(var+1e-5f));
}

// FUSED GAT v4: single-phase, latency-optimized, XCD-GRAPH-AFFINE.
// R6/R7: per-graph gather working set fits one XCD's 4MB L2 — grid = 8*bpg
// (padded), work = (b&7)*bpg + b/8 -> graph g runs entirely on XCD g under
// round-robin dispatch; gathers are XCD-L2 hits (441->420us confirmed).
template<int H,int F,int EB>
__global__ __launch_bounds__(256) void k_gat_fused(
    const float* __restrict__ xp, const float* __restrict__ als,
    const float* __restrict__ ald, const int* __restrict__ rowptr,
    const int* __restrict__ cnt, const int* __restrict__ esrc,
    const float* __restrict__ bias, float* __restrict__ out,
    float* __restrict__ accum, int RPG, int bpg){
  constexpr int C = H*F, C4 = C/4;
  constexpr int NPB = 256/C4;
  __shared__ float psum[4][C], psq[4][C];
  int tid = threadIdx.x;
  int nl = tid / C4, p = tid % C4;
  int work = (blockIdx.x & 7)*(gridDim.x >> 3) + (blockIdx.x >> 3);
  int g = work / bpg, t = work - g*bpg;
  int loc = t*NPB + nl;
  int node = g*RPG + loc;
  int hh = (4*p)/F;
  const float4* xp4 = (const float4*)xp;
  float4 r = make_float4(0.f,0.f,0.f,0.f);
  bool valid = loc < RPG;
  if(valid){
    float dvh = ald[node*H+hh];
    float sw  = expf(lrelu(als[node*H+hh] + dvh));   // self-loop weight
    float4 xs = xp4[(size_t)node*C4 + p];
    float den = sw;
    float ax=sw*xs.x, ay=sw*xs.y, az=sw*xs.z, aw_=sw*xs.w;
    int r0  = rowptr[node];
    int deg = cnt[node];
    for(int j=0; j<deg; j+=EB){
      int idx[EB]; float wv[EB]; float4 v[EB];
#pragma unroll
      for(int q=0;q<EB;q++)
        idx[q] = (j+q < deg) ? esrc[r0+j+q] : node;   // masked slots: safe dup
#pragma unroll
      for(int q=0;q<EB;q++)
        wv[q] = als[idx[q]*H+hh];
#pragma unroll
      for(int q=0;q<EB;q++)
        v[q] = xp4[(size_t)idx[q]*C4 + p];
#pragma unroll
      for(int q=0;q<EB;q++){
        float w = (j+q < deg) ? expf(lrelu(wv[q] + dvh)) : 0.f;
        den += w;
        ax += w*v[q].x; ay += w*v[q].y; az += w*v[q].z; aw_ += w*v[q].w;
      }
    }
    float inv = 1.f / den;
    float4 bv = ((const float4*)bias)[p];
    r.x=ax*inv+bv.x; r.y=ay*inv+bv.y; r.z=az*inv+bv.z; r.w=aw_*inv+bv.w;
    ((float4*)out)[(size_t)node*C4 + p] = r;
  }
  // ---- fused inorm stats (whole block belongs to graph g; invalid lanes r=0)
  float sx=r.x, sy=r.y, sz=r.z, sw2=r.w;
  float qx=r.x*r.x, qy=r.y*r.y, qz=r.z*r.z, qw=r.w*r.w;
#pragma unroll
  for(int off=C4; off<64; off<<=1){
    sx += __shfl_down(sx, off, 64); sy += __shfl_down(sy, off, 64);
    sz += __shfl_down(sz, off, 64); sw2 += __shfl_down(sw2, off, 64);
    qx += __shfl_down(qx, off, 64); qy += __shfl_down(qy, off, 64);
    qz += __shfl_down(qz, off, 64); qw += __shfl_down(qw, off, 64);
  }
  int lane = tid & 63, w = tid >> 6;
  if(lane < C4){
    psum[w][4*lane+0]=sx; psum[w][4*lane+1]=sy;
    psum[w][4*lane+2]=sz; psum[w][4*lane+3]=sw2;
    psq[w][4*lane+0]=qx;  psq[w][4*lane+1]=qy;
    psq[w][4*lane+2]=qz;  psq[w][4*lane+3]=qw;
  }
  __syncthreads();
  if(tid < C){
    float ts = psum[0][tid]+psum[1][tid]+psum[2][tid]+psum[3][tid];
    float tq = psq[0][tid]+psq[1][tid]+psq[2][tid]+psq[3][tid];
    atomicAdd(&accum[(g*C+tid)*2],   ts);
    atomicAdd(&accum[(g*C+tid)*2+1], tq);
  }
}

// R9 MERGED post-topk dispatch: blocks [0,ncomp) = edge compaction (reads
// newid), blocks [ncomp,..) = dense row-GEMM with fused pool-gather +
// deferred-inorm + attention-logit epilogue (reads oldid/scale). Both halves
// depend only on topk and are mutually independent -> compact hides under
// the longer gemm. LDS is a 16KB union. Compact g = blk&7 -> XCD-affine cnt.
template<int K,int CO,int NPG,int H,int CHUNK>
__global__ __launch_bounds__(256) void k_cpt_gemm(
    const int* __restrict__ se, const int* __restrict__ de,
    const int* __restrict__ gcnt_in, int fixed_in, int reg_in,
    const int* __restrict__ newid, int* __restrict__ gcnt_out,
    int* __restrict__ ons, int* __restrict__ ond, int reg_out,
    int* __restrict__ cnt, int ncomp,
    const float* __restrict__ X, const float* __restrict__ naccum, int nRPG,
    const int* __restrict__ oldid, const float* __restrict__ scale,
    const float* __restrict__ W, float* __restrict__ Y,
    const float* __restrict__ a_s, const float* __restrict__ a_d,
    float* __restrict__ als, float* __restrict__ ald, int n){
  constexpr int SUB = 256/CO;
  constexpr int NB = SUB*NPG;
  static_assert(NB*K <= 2*CHUNK, "xs must fit the union");
  __shared__ int sm[2*CHUNK];
  __shared__ int run, tbase;
  __shared__ float ps[4][NPG], pd[4][NPG];
  int tid = threadIdx.x;
  if((int)blockIdx.x < ncomp){
    // ---------------- compact half ----------------
    int* s_a = sm;
    int* s_b = sm + CHUNK;
    if(tid == 0) run = 0;
    __syncthreads();
    int blk = blockIdx.x;
    int g = blk & 7, t = blk >> 3;     // g == blockIdx%8 -> XCD-affine
    int mg = gcnt_in ? gcnt_in[g] : fixed_in;
    if(mg > reg_in) mg = reg_in;
    int base_l = t*CHUNK;
    if(base_l < mg){
      const int4* de4 = (const int4*)(de + (size_t)g*reg_in + base_l);
      const int4* se4 = (const int4*)(se + (size_t)g*reg_in + base_l);
      int4 BD[CHUNK/1024], BS[CHUNK/1024];
#pragma unroll
      for(int j=0;j<CHUNK/1024;j++){ BD[j]=de4[j*256+tid]; BS[j]=se4[j*256+tid]; }
      int cl = 0;
#pragma unroll
      for(int j=0;j<CHUNK/1024;j++){
        int eb = base_l + (j*256+tid)*4;
        int dd[4]={BD[j].x,BD[j].y,BD[j].z,BD[j].w};
        int ss[4]={BS[j].x,BS[j].y,BS[j].z,BS[j].w};
#pragma unroll
        for(int q=0;q<4;q++){
          if(eb+q < mg){
            int a = newid[ss[q]], b = newid[dd[q]];
            if(a>=0 && b>=0){ cl++; atomicAdd(&cnt[b], 1); }
          }
        }
      }
      int p0 = 0;
      if(cl) p0 = atomicAdd(&run, cl);
#pragma unroll
      for(int j=0;j<CHUNK/1024;j++){
        int eb = base_l + (j*256+tid)*4;
        int dd[4]={BD[j].x,BD[j].y,BD[j].z,BD[j].w};
        int ss[4]={BS[j].x,BS[j].y,BS[j].z,BS[j].w};
#pragma unroll
        for(int q=0;q<4;q++){
          if(eb+q < mg){
            int a = newid[ss[q]], b = newid[dd[q]];
            if(a>=0 && b>=0){ s_a[p0]=a; s_b[p0]=b; p0++; }
          }
        }
      }
    }
    __syncthreads();
    int ns = run;
    if(tid==0) tbase = ns ? atomicAdd(&gcnt_out[blockIdx.x & 7], ns) : 0;
    __syncthreads();
    int tb = tbase;
    int g2 = blockIdx.x & 7;
    for(int j=tid; j<ns; j+=256){
      int s2 = tb + j;
      if(s2 < reg_out){ ons[(size_t)g2*reg_out+s2]=s_a[j]; ond[(size_t)g2*reg_out+s2]=s_b[j]; }
    }
    return;
  }
  // ---------------- gemm half ----------------
  float (*xs)[K] = reinterpret_cast<float(*)[K]>(sm);
  int c = tid % CO, sg = tid / CO;
  int n0 = ((int)blockIdx.x - ncomp) * NB;
  for(int idx=tid; idx<NB*K; idx+=256){
    int r = idx / K, k = idx % K;
    int row = n0 + r;
    float v = 0.f;
    if(row < n){
      int orow = oldid[row];
      int og = orow / nRPG;
      v = inorm_of(naccum, og*K + k, (float)nRPG, X[(size_t)orow*K + k]) * scale[row];
    }
    xs[r][k] = v;
  }
  __syncthreads();
  float acc[NPG];
#pragma unroll
  for(int q=0;q<NPG;q++) acc[q]=0.f;
  for(int k=0;k<K;k++){
    float wv = W[(size_t)k*CO + c];
#pragma unroll
    for(int q=0;q<NPG;q++) acc[q] += xs[sg*NPG+q][k]*wv;
  }
  float asc = a_s[c], adc = a_d[c];
  float vs[NPG], vd[NPG];
#pragma unroll
  for(int q=0;q<NPG;q++){
    int row = n0 + sg*NPG + q;
    if(row < n) Y[(size_t)row*CO + c] = acc[q];
    vs[q] = acc[q]*asc; vd[q] = acc[q]*adc;
  }
#pragma unroll
  for(int o=32;o>0;o>>=1){
#pragma unroll
    for(int q=0;q<NPG;q++){
      vs[q] += __shfl_down(vs[q], o, 64);
      vd[q] += __shfl_down(vd[q], o, 64);
    }
  }
  int lane = tid & 63, w = tid >> 6;
  if(H == 2){
    if(lane == 0){
      int sg_ = w >> 1, h = w & 1;
#pragma unroll
      for(int q=0;q<NPG;q++){
        int row = n0 + sg_*NPG + q;
        if(row < n){ als[row*2+h] = vs[q]; ald[row*2+h] = vd[q]; }
      }
    }
  } else {
    if(lane == 0){
#pragma unroll
      for(int q=0;q<NPG;q++){ ps[w][q]=vs[q]; pd[w][q]=vd[q]; }
    }
    __syncthreads();
    if(tid < NPG){
      float s=0.f, d=0.f;
      for(int ww=0;ww<4;ww++){ s+=ps[ww][tid]; d+=pd[ww][tid]; }
      int row = n0 + tid;
      if(row < n){ als[row]=s; ald[row]=d; }
    }
  }
}

// fused inorm + ELU + pool score + orderable key (stages 1/2). SCORE-ONLY.
// R10: shuffle reduction — C=32 rows live in a 32-lane subgroup (zero
// barriers); C=128 rows span 2 waves (1 barrier).
template<int C>
__global__ __launch_bounds__(256) void k_inorm_score(
    const float* __restrict__ x, const float* __restrict__ accum,
    const float* __restrict__ p, int R, int total,
    float* __restrict__ score, unsigned* __restrict__ u){
  int tid = threadIdx.x;
  int i = blockIdx.x*256 + tid;
  int c = tid & (C-1);
  bool act = i < total;
  float v = 0.f, pv = 0.f;
  if(act){
    int g = i / (R*C);
    v = inorm_of(accum, g*C+c, (float)R, x[i]);
    pv = p[c];
  }
  float vp = v*pv, pp = pv*pv;
  if(C <= 64){
#pragma unroll
    for(int o=C/2;o>0;o>>=1){
      vp += __shfl_down(vp, o, C);
      pp += __shfl_down(pp, o, C);
    }
    if(act && c==0){
      float sv = tanhf(vp*rsqrtf(pp));
      int row = i / C;
      score[row] = sv;
      unsigned bts = __float_as_uint(sv);
      u[row] = (bts & 0x80000000u) ? ~bts : (bts | 0x80000000u);
    }
  } else {
    __shared__ float sv_[4], sp_[4];
#pragma unroll
    for(int o=32;o>0;o>>=1){
      vp += __shfl_down(vp, o, 64);
      pp += __shfl_down(pp, o, 64);
    }
    int lane = tid & 63, w = tid >> 6;
    if(lane==0){ sv_[w]=vp; sp_[w]=pp; }
    __syncthreads();
    if(act && c==0){   // c==0 -> lane0 of waves 0 and 2 (row spans w, w+1)
      float tv = sv_[w]+sv_[w+1], tp = sp_[w]+sp_[w+1];
      float sv = tanhf(tv*rsqrtf(tp));
      int row = i / C;
      score[row] = sv;
      unsigned bts = __float_as_uint(sv);
      u[row] = (bts & 0x80000000u) ? ~bts : (bts | 0x80000000u);
    }
  }
}

// MERGED top-k: radix select (exact k-th + ties) THEN deterministic
// compaction, one block per graph.
__global__ __launch_bounds__(1024) void k_topk(
    const unsigned* __restrict__ u, const float* __restrict__ score,
    int R, int Ksel, int* __restrict__ newid, int* __restrict__ oldid,
    float* __restrict__ scale){
  __shared__ int hist[2048];
  __shared__ int seg[32];
  __shared__ int sh_b, sh_k;
  __shared__ int wsA[16], wsB[16];
  __shared__ int carr0, carr1;
  int g = blockIdx.x, tid = threadIdx.x, lane = tid&63, w = tid>>6;
  const unsigned* ug = u + (size_t)g*R;
  // ---- phase 1: select
  unsigned prefix = 0;
  int K = Ksel;
  for(int lev=0; lev<3; lev++){
    int shf = (lev==0)?21:((lev==1)?10:0);
    int nb  = (lev==2)?1024:2048;
    for(int i=tid;i<2048;i+=1024) hist[i]=0;
    __syncthreads();
    for(int i=tid;i<R;i+=1024){
      unsigned v = ug[i];
      bool ok = (lev==0) || (lev==1 && (v>>21)==prefix) || (lev==2 && (v>>10)==prefix);
      if(ok) atomicAdd(&hist[(v>>shf)&(nb-1)], 1);
    }
    __syncthreads();
    int W = nb/32;
    if(tid<32){ int s=0; int lo=nb-W*(tid+1); for(int b=lo;b<lo+W;b++) s+=hist[b]; seg[tid]=s; }
    __syncthreads();
    if(tid==0){
      int kk=K, sgi=0;
      while(seg[sgi]<kk){ kk-=seg[sgi]; sgi++; }
      int b = nb-1-W*sgi;
      while(hist[b]<kk){ kk-=hist[b]; b--; }
      sh_b=b; sh_k=kk;
    }
    __syncthreads();
    int b = sh_b; K = sh_k;
    if(lev==0) prefix = (unsigned)b;
    else if(lev==1) prefix = (prefix<<11) | (unsigned)b;
    else prefix = (prefix<<10) | (unsigned)b;
    __syncthreads();
  }
  unsigned thr = prefix;
  int need = K;
  // ---- phase 2: compact (u>thr plus lowest-index u==thr; lax.top_k ties)
  if(tid==0){ carr0=0; carr1=0; }
  __syncthreads();
  for(int bb=0; bb<R; bb+=1024){
    int i = bb + tid; bool in = i < R;
    unsigned uv = in ? ug[i] : 0u;
    int eq = (in && uv==thr) ? 1:0;
    int gt = (in && uv>thr) ? 1:0;
    int inc = eq;
    for(int o=1;o<64;o<<=1){ int t=__shfl_up(inc,o,64); if(lane>=o) inc+=t; }
    if(lane==63) wsA[w]=inc;
    __syncthreads();
    int wb=0; for(int k=0;k<w;k++) wb+=wsA[k];
    int eq_excl = carr0 + wb + inc - eq;
    int take = (gt || (eq && eq_excl<need)) ? 1 : 0;
    int inc2 = take;
    for(int o=1;o<64;o<<=1){ int t=__shfl_up(inc2,o,64); if(lane>=o) inc2+=t; }
    if(lane==63) wsB[w]=inc2;
    __syncthreads();
    int wb2=0; for(int k=0;k<w;k++) wb2+=wsB[k];
    int pos = carr1 + wb2 + inc2 - take;
    if(take){
      int nr = g*Ksel + pos;
      newid[(size_t)g*R+i] = nr;
      oldid[nr] = g*R+i;
      scale[nr] = score[(size_t)g*R+i];
    }
    __syncthreads();
    if(tid==1023){ carr0 += wb + inc; carr1 += wb2 + inc2; }
    __syncthreads();
  }
}

// fused gate pipeline with stage-3 inorm on input, 8 rows/block:
// each 64-lane group computes TWO rows sharing one gw1 stream.
__global__ __launch_bounds__(256) void k_gate_fused(
    const float* __restrict__ X, const float* __restrict__ accum,
    const float* __restrict__ gw1, const float* __restrict__ gb1,
    const float* __restrict__ gw2, const float* __restrict__ gb2,
    float* __restrict__ gatev, int n){
  __shared__ float xs[8][256];
  int tid = threadIdx.x;
  int n0 = blockIdx.x*8;
  for(int idx=tid; idx<2048; idx+=256){
    int r = idx >> 8, k = idx & 255;
    int row = n0 + r;
    float v = 0.f;
    if(row < n){
      int g = row / KP2;
      v = inorm_of(accum, g*256+k, (float)KP2, X[(size_t)row*256 + k]);
    }
    xs[r][k] = v;
  }
  __syncthreads();
  int sg = tid >> 6, c = tid & 63;
  float a0 = 0.f, a1 = 0.f;
#pragma unroll 8
  for(int k=0;k<256;k++){
    float w = gw1[k*64+c];
    a0 = fmaf(xs[sg][k],   w, a0);
    a1 = fmaf(xs[sg+4][k], w, a1);
  }
  float gb = gb1[c], g2 = gw2[c];
  float v0 = eluf(a0 + gb) * g2;
  float v1 = eluf(a1 + gb) * g2;
#pragma unroll
  for(int o=32;o>0;o>>=1){
    v0 += __shfl_down(v0, o, 64);
    v1 += __shfl_down(v1, o, 64);
  }
  if(c==0){
    int r0 = n0 + sg, r1 = n0 + sg + 4;
    if(r0 < n) gatev[r0] = v0 + gb2[0];
    if(r1 < n) gatev[r1] = v1 + gb2[0];
  }
}

// MERGED h-GEMM + attention accumulate; 8 rows/block halves the aw stream.
__global__ __launch_bounds__(256) void k_attn_gemm(
    const float* __restrict__ X, const float* __restrict__ accum,
    const float* __restrict__ W, const float* __restrict__ bias,
    const float* __restrict__ gatev, float* __restrict__ gvec){
  __shared__ float xs[8][256];
  __shared__ float red[256];
  int tid = threadIdx.x;
  int t = blockIdx.x, g = blockIdx.y;
  int r0 = t*8;
  float mx = -1e30f;
  for(int r=tid;r<KP2;r+=256) mx = fmaxf(mx, gatev[g*KP2+r]);
  red[tid]=mx; __syncthreads();
  for(int s=128;s>0;s>>=1){ if(tid<s) red[tid]=fmaxf(red[tid],red[tid+s]); __syncthreads(); }
  mx = red[0]; __syncthreads();
  float sm=0.f;
  for(int r=tid;r<KP2;r+=256) sm += expf(gatev[g*KP2+r]-mx);
  red[tid]=sm; __syncthreads();
  for(int s=128;s>0;s>>=1){ if(tid<s) red[tid]+=red[tid+s]; __syncthreads(); }
  float inv = 1.f/red[0];
  __syncthreads();
  for(int idx=tid; idx<2048; idx+=256){
    int r = idx >> 8, k = idx & 255;
    int lr = r0 + r;
    float v = 0.f;
    if(lr < KP2){
      int row = g*KP2 + lr;
      v = inorm_of(accum, g*256+k, (float)KP2, X[(size_t)row*256 + k]);
    }
    xs[r][k] = v;
  }
  __syncthreads();
  int c = tid;
  float acc[8];
#pragma unroll
  for(int q=0;q<8;q++) acc[q]=0.f;
  for(int k=0;k<256;k++){
    float wv = W[(size_t)k*256 + c];
#pragma unroll
    for(int q=0;q<8;q++) acc[q] += xs[q][k]*wv;
  }
  float bv = bias[c];
  float tot = 0.f;
#pragma unroll
  for(int q=0;q<8;q++){
    int lr = r0 + q;
    if(lr < KP2){
      float h = eluf(acc[q] + bv);
      tot += expf(gatev[g*KP2+lr]-mx) * h;
    }
  }
  atomicAdd(&gvec[g*256+c], tot*inv);
}

// tiny-n tail MLP: compile-time K fully pipelined (R13/R2-confirmed: keep
// split — the 8-block merged tail regressed to 60+us latency-serialized
// weight streams, OccupancyPercent 0.33%)
template<int K,int CO,int ACT>
__global__ __launch_bounds__(256) void k_mlp_t(
    const float* __restrict__ X, const float* __restrict__ W,
    const float* __restrict__ b, float* __restrict__ Y, int n){
  int i = blockIdx.x*256+threadIdx.x;
  if(i>=n*CO) return;
  int r=i/CO, c=i%CO;
  const float* xr = X + (size_t)r*K;
  float a=0.f;
#pragma unroll 16
  for(int k=0;k<K;k++) a = fmaf(xr[k], W[(size_t)k*CO+c], a);
  a += b[c];
  if(ACT) a = eluf(a);
  Y[i]=a;
}

__global__ __launch_bounds__(64) void k_head(
    const float* __restrict__ z2, const float* __restrict__ w3,
    const float* __restrict__ b3, float* __restrict__ out){
  __shared__ float zc[10]; __shared__ float mred, sred;
  int g=blockIdx.x, tid=threadIdx.x;
  if(tid<10){
    float a=0.f;
#pragma unroll 16
    for(int k=0;k<128;k++) a += z2[g*128+k]*w3[k*10+tid];
    zc[tid]=a+b3[tid];
  }
  __syncthreads();
  if(tid==0){
    float m=zc[0];
    for(int k=1;k<10;k++) m=fmaxf(m,zc[k]);
    float s=0.f;
    for(int k=0;k<10;k++) s+=expf(zc[k]-m);
    mred=m; sred=logf(s);
  }
  __syncthreads();
  if(tid<10) out[g*10+tid]=zc[tid]-mred-sred;
}

} // namespace pk

extern "C" void kernel_launch(void* const* d_in, const int* in_sizes, int n_in,
                              void* d_out, int out_size, void* d_ws, size_t ws_size,
                              hipStream_t stream){
  using namespace pk;
  (void)in_sizes; (void)n_in; (void)out_size;
  const float* pos = (const float*)d_in[0];
  const int*   src = (const int*)d_in[1];
  const int*   dst = (const int*)d_in[2];
  const float* W1  = (const float*)d_in[3];
  const float* as1 = (const float*)d_in[4];
  const float* ad1 = (const float*)d_in[5];
  const float* b1  = (const float*)d_in[6];
  const float* p1  = (const float*)d_in[7];
  const float* W2  = (const float*)d_in[8];
  const float* as2 = (const float*)d_in[9];
  const float* ad2 = (const float*)d_in[10];
  const float* b2  = (const float*)d_in[11];
  const float* p2  = (const float*)d_in[12];
  const float* W3  = (const float*)d_in[13];
  const float* as3 = (const float*)d_in[14];
  const float* ad3 = (const float*)d_in[15];
  const float* b3  = (const float*)d_in[16];
  const float* gw1 = (const float*)d_in[17];
  const float* gb1 = (const float*)d_in[18];
  const float* gw2 = (const float*)d_in[19];
  const float* gb2 = (const float*)d_in[20];
  const float* aw  = (const float*)d_in[21];
  const float* ab  = (const float*)d_in[22];
  const float* w1  = (const float*)d_in[23];
  const float* bb1 = (const float*)d_in[24];
  const float* w2  = (const float*)d_in[25];
  const float* bb2 = (const float*)d_in[26];
  const float* w3  = (const float*)d_in[27];
  const float* bb3 = (const float*)d_in[28];
  float* out = (float*)d_out;

  char* base = (char*)d_ws; size_t off = 0;
  auto alloc = [&](size_t nbytes)->char*{
    char* p = base + off; off = (off + nbytes + 255) & ~(size_t)255; return p;
  };
  // --- zero-init region (one memset) ---
  int*   cnt2  = (int*)alloc((size_t)NN2*4);
  int*   cnt3  = (int*)alloc((size_t)NN3*4);
  int*   ecnt2 = (int*)alloc((size_t)BG*4);
  int*   ecnt3 = (int*)alloc((size_t)BG*4);
  float* acc1  = (float*)alloc((size_t)BG*32*2*4);
  float* acc2  = (float*)alloc((size_t)BG*128*2*4);
  float* acc3  = (float*)alloc((size_t)BG*256*2*4);
  float* gvec  = (float*)alloc((size_t)BG*256*4);
  int*   bcur1 = (int*)alloc((size_t)BG*NTILE*4);
  size_t zend = off;
  // --- 0xFF-init region (newid = -1, one memset) ---
  int*   newid1 = (int*)alloc((size_t)NB1*4);
  int*   newid2 = (int*)alloc((size_t)NN2*4);
  size_t fstart = (size_t)((char*)newid1 - base);
  size_t fend = off;
  // --- plain scratch ---
  int*      cnt1   = (int*)alloc((size_t)NB1*4);           // dense-written
  int*      bpk1   = (int*)alloc((size_t)BG*NTILE*BKT*4);  // bucket-packed edges
  float*    xp1    = (float*)alloc((size_t)NB1*32*4);
  float*    als1   = (float*)alloc((size_t)NB1*2*4);
  float*    ald1   = (float*)alloc((size_t)NB1*2*4);
  int*      rowptr1= (int*)alloc((size_t)NB1*4);
  int*      esrc1  = (int*)alloc((size_t)NE*4);
  float*    out1   = (float*)alloc((size_t)NB1*32*4);
  float*    score1 = (float*)alloc((size_t)NB1*4);
  unsigned* u1     = (unsigned*)alloc((size_t)NB1*4);
  int*      oldid1 = (int*)alloc((size_t)NN2*4);
  float*    scale1 = (float*)alloc((size_t)NN2*4);
  int*      ns2    = (int*)alloc((size_t)CAP2*4);
  int*      nd2    = (int*)alloc((size_t)CAP2*4);
  int*      rowptr2= (int*)alloc((size_t)NN2*4);
  int*      cursor2= (int*)alloc((size_t)NN2*4);
  int*      esrc2  = (int*)alloc((size_t)CAP2*4);
  float*    xp2    = (float*)alloc((size_t)NN2*128*4);
  float*    als2   = (float*)alloc((size_t)NN2*2*4);
  float*    ald2   = (float*)alloc((size_t)NN2*2*4);
  float*    out2   = (float*)alloc((size_t)NN2*128*4);
  float*    score2 = (float*)alloc((size_t)NN2*4);
  unsigned* u2     = (unsigned*)alloc((size_t)NN2*4);
  int*      oldid2 = (int*)alloc((size_t)NN3*4);
  float*    scale2 = (float*)alloc((size_t)NN3*4);
  int*      ns3    = (int*)alloc((size_t)CAP3*4);
  int*      nd3    = (int*)alloc((size_t)CAP3*4);
  int*      rowptr3= (int*)alloc((size_t)NN3*4);
  int*      esrc3  = (int*)alloc((size_t)CAP3*4);
  float*    xp3    = (float*)alloc((size_t)NN3*256*4);
  float*    als3   = (float*)alloc((size_t)NN3*4);
  float*    ald3   = (float*)alloc((size_t)NN3*4);
  float*    out3   = (float*)alloc((size_t)NN3*256*4);
  float*    gatev  = (float*)alloc((size_t)NN3*4);
  float*    z1     = (float*)alloc((size_t)BG*512*4);
  float*    z2     = (float*)alloc((size_t)BG*128*4);
  if(off > ws_size) return;  // workspace too small: fail visibly

  auto cdiv = [](int a, int b){ return (a+b-1)/b; };

  hipMemsetAsync(base, 0, zend, stream);
  hipMemsetAsync(base + fstart, 0xFF, fend - fstart, stream);

  // ---------------- stage 1: GAT(3->32, H=2,F=16) ----------------
  k_s1_front<<<192,1024,0,stream>>>(pos,W1,as1,ad1,xp1,als1,ald1,src,dst,bcur1,bpk1);
  k_scatter_b<<<256,1024,0,stream>>>(bcur1,bpk1,cnt1,rowptr1,esrc1);
  k_gat_fused<2,16,16><<<2048,256,0,stream>>>(xp1,als1,ald1,rowptr1,cnt1,esrc1,b1,out1,acc1,NPG1,256);
  k_inorm_score<32><<<cdiv(NB1*32,256),256,0,stream>>>(out1,acc1,p1,8192,NB1*32,score1,u1);
  // ---------------- pool 1 (k=2458) ----------------
  k_topk<<<BG,1024,0,stream>>>(u1,score1,8192,KP1,newid1,oldid1,scale1);
  // merged: compact (512 blocks, chunk 2048) + stage-2 gemm (2458 blocks)
  k_cpt_gemm<32,128,4,2,2048><<<512+cdiv(NN2,8),256,0,stream>>>(
      src,dst,nullptr,EPG1,EPG1,newid1,ecnt2,ns2,nd2,REG2,cnt2,512,
      out1,acc1,NPG1,oldid1,scale1,W2,xp2,as2,ad2,als2,ald2,NN2);
  k_scan_w<10><<<BG,256,0,stream>>>(cnt2,KP1,REG2,rowptr2,cursor2);
  k_scatter_r<<<CAP2/256,256,0,stream>>>(ns2,nd2,ecnt2,REG2,cursor2,esrc2);
  // bpg = ceil(2458/8)=308 -> grid 2464, graph g pinned to XCD g
  k_gat_fused<2,64,8><<<8*308,256,0,stream>>>(xp2,als2,ald2,rowptr2,cnt2,esrc2,b2,out2,acc2,KP1,308);
  k_inorm_score<128><<<cdiv(NN2*128,256),256,0,stream>>>(out2,acc2,p2,KP1,NN2*128,score2,u2);
  // ---------------- pool 2 (k=738) ----------------
  k_topk<<<BG,1024,0,stream>>>(u2,score2,KP1,KP2,newid2,oldid2,scale2);
  // merged: compact (64 blocks, chunk 2048) + stage-3 gemm (1476 blocks)
  k_cpt_gemm<128,256,4,1,2048><<<64+cdiv(NN3,4),256,0,stream>>>(
      ns2,nd2,ecnt2,0,REG2,newid2,ecnt3,ns3,nd3,REG3,cnt3,64,
      out2,acc2,KP1,oldid2,scale2,W3,xp3,as3,ad3,als3,ald3,NN3);
  // stage-3 scan+scatter merged (parallelism-neutral at ~8.8K edges)
  k_scan_scatter<1><<<BG,1024,0,stream>>>(cnt3,KP2,REG3,rowptr3,ns3,nd3,ecnt3,REG3,esrc3);
  // bpg=185 blocks/graph, grid 1480, graph g pinned to XCD g
  k_gat_fused<1,256,4><<<8*185,256,0,stream>>>(xp3,als3,ald3,rowptr3,cnt3,esrc3,b3,out3,acc3,KP2,185);
  // ---------------- global attention + MLP head (stage-3 norm fused in) ----
  k_gate_fused<<<cdiv(NN3,8),256,0,stream>>>(out3,acc3,gw1,gb1,gw2,gb2,gatev,NN3);
  k_attn_gemm<<<dim3(cdiv(KP2,8),BG),256,0,stream>>>(out3,acc3,aw,ab,gatev,gvec);
  k_mlp_t<256,512,1><<<cdiv(BG*512,256),256,0,stream>>>(gvec,w1,bb1,z1,BG);
  k_mlp_t<512,128,1><<<cdiv(BG*128,256),256,0,stream>>>(z1,w2,bb2,z2,BG);
  k_head<<<BG,64,0,stream>>>(z2,w3,bb3,out);
}